// Round 15
// baseline (366.617 us; speedup 1.0000x reference)
//
#include <hip/hip_runtime.h>
#include <hip/hip_bf16.h>

#define N_NODES 100000
#define N_EDGES 3200000
#define N_GRAPHS 256
#define NB_BUCKETS 196      // ceil(100000 / 512)
#define BSHIFT 9            // 512 nodes per bucket
#define NBLK 256            // blocks for hist/bin passes
#define SCAN_BLKS 49        // 50176 / 1024
#define CSR_CAP 22528       // LDS staging capacity (88 KB); avg bucket 16.4K edges

// ---------------- workspace layout (bytes) ----------------
#define OFF_SUMS      0u            // float[256*64] pool sums (zeroed in hist)
#define OFF_CNTF      65536u        // float[256] pool counts (zeroed in hist)
#define ZERO_BYTES    66560u
#define OFF_HIST      66560u        // int[196*256] (bucket-major) per-(bucket,block) counts
#define OFF_BSUM      267264u       // int[64] scan block sums
#define OFF_ROWPTR    267776u       // int[N+1]
#define OFF_DINV      668160u       // float[N]
#define OFF_COL       1068544u     // int[E]
#define OFF_XS1       13868544u     // bf16[N*8]
#define OFF_WPRE      15468544u     // bf16 prepacked W2^T[128][72] + W3^T[64][136] (35840 B)
#define OFF_BUFQ      20268544u     // bf16 xs2 [N*64], later bf16 ys [N*64]
#define OFF_BUFR      45868544u     // bf16 z2 [N*64], later bf16 z3 [N*64]
#define OFF_BUFP      71468544u     // ALIASED: packed[E] only (h2 lives in LDS)
#define OFF_PAIRS     OFF_BUFP
// total ~97 MB

#define WPRE_W3OFF 9216             // ushort offset of W3^T inside wpre (128*72)
#define WPRE_TOT   17920            // total ushorts (9216 + 64*136)

typedef __attribute__((ext_vector_type(8))) short bf16x8;   // MFMA A/B frag (4 VGPRs)
typedef __attribute__((ext_vector_type(4))) float f32x4;    // MFMA C/D frag

// round-to-nearest-even float -> bf16 (values are finite; no NaN guard needed)
__device__ __forceinline__ unsigned short f2bf(float f) {
    unsigned u = __float_as_uint(f);
    return (unsigned short)((u + 0x7fffu + ((u >> 16) & 1u)) >> 16);
}

__device__ __forceinline__ float bf2f(unsigned short h) {
    return __uint_as_float(((unsigned)h) << 16);
}

// unpack uint4 (8 bf16) and accumulate m * value into a[0..7] (fp32)
__device__ __forceinline__ void acc_bf8(uint4 v, float m, float* a) {
    a[0] += m * __uint_as_float(v.x << 16);
    a[1] += m * __uint_as_float(v.x & 0xffff0000u);
    a[2] += m * __uint_as_float(v.y << 16);
    a[3] += m * __uint_as_float(v.y & 0xffff0000u);
    a[4] += m * __uint_as_float(v.z << 16);
    a[5] += m * __uint_as_float(v.z & 0xffff0000u);
    a[6] += m * __uint_as_float(v.w << 16);
    a[7] += m * __uint_as_float(v.w & 0xffff0000u);
}

// ---- P1: per-(bucket,block) histogram of dst. Also zeroes the pool
// accumulators.
__global__ __launch_bounds__(256) void hist_kernel(const int* __restrict__ dst,
                                                   int* __restrict__ hist,
                                                   int* __restrict__ zbase,
                                                   int E, int epb) {
    __shared__ int h[NB_BUCKETS];
    int t = threadIdx.x, blk = blockIdx.x;
    int gid = blk * 256 + t;
    if (gid < (int)(ZERO_BYTES / 4)) zbase[gid] = 0;
    if (t < NB_BUCKETS) h[t] = 0;
    __syncthreads();
    int e0 = blk * epb, e1 = min(e0 + epb, E);
    for (int e = e0 + t; e < e1; e += 256)
        atomicAdd(&h[__builtin_nontemporal_load(&dst[e]) >> BSHIFT], 1);
    __syncthreads();
    if (t < NB_BUCKETS) hist[t * NBLK + blk] = h[t];
}

// ---- P2: block-local exclusive scan of hist[50176] + per-block sums.
// Idle threads also pre-pack W2^T/W3^T to bf16 (one-time; feeds mgemm23).
__global__ __launch_bounds__(1024) void scanhA_kernel(int* __restrict__ hist,
                                                      int* __restrict__ bsum,
                                                      const float* __restrict__ W2,
                                                      const float* __restrict__ W3,
                                                      unsigned short* __restrict__ wpre) {
    __shared__ int s[1024];
    int t = threadIdx.x;
    int i = blockIdx.x * 1024 + t;     // 49*1024 == 50176 exactly
    // weight prepack (first 16384 global threads, overlaps the scan)
    if (i < 8192) {                    // W2^T [128][72]: Wt2[m][k] = W2[k][m]
        int m = i >> 6, k = i & 63;
        wpre[m * 72 + k] = f2bf(W2[k * 128 + m]);
    } else if (i < 16384) {            // W3^T [64][136]: Wt3[m][k] = W3[k][m]
        int ii = i - 8192;
        int m = ii >> 7, k = ii & 127;
        wpre[WPRE_W3OFF + m * 136 + k] = f2bf(W3[k * 64 + m]);
    }
    int v = hist[i];
    s[t] = v;
    __syncthreads();
    for (int off = 1; off < 1024; off <<= 1) {
        int add = (t >= off) ? s[t - off] : 0;
        __syncthreads();
        s[t] += add;
        __syncthreads();
    }
    hist[i] = s[t] - v;                // block-local exclusive
    if (t == 1023) bsum[blockIdx.x] = s[t];
}

// ---- P3: bin edges, PACKED (dl<<17 | src), local offset scan.
__global__ __launch_bounds__(256) void bin_kernel(const int* __restrict__ src,
                                                  const int* __restrict__ dst,
                                                  const int* __restrict__ hist,
                                                  const int* __restrict__ bsum,
                                                  int* __restrict__ packed, int E, int epb) {
    __shared__ int cur[NB_BUCKETS];
    __shared__ int boffL[SCAN_BLKS];
    int t = threadIdx.x, blk = blockIdx.x;
    if (t < 64) {
        int orig = (t < SCAN_BLKS) ? bsum[t] : 0;
        int v = orig;
        for (int off = 1; off < 64; off <<= 1) {
            int up = __shfl_up(v, off);
            if (t >= off) v += up;
        }
        if (t < SCAN_BLKS) boffL[t] = v - orig;   // exclusive
    }
    __syncthreads();
    if (t < NB_BUCKETS) {
        int i = t * NBLK + blk;
        cur[t] = hist[i] + boffL[i >> 10];
    }
    __syncthreads();
    int e0 = blk * epb, e1 = min(e0 + epb, E);
    for (int e = e0 + t; e < e1; e += 256) {
        int d = __builtin_nontemporal_load(&dst[e]);
        int sv = __builtin_nontemporal_load(&src[e]);
        int pos = atomicAdd(&cur[d >> BSHIFT], 1);
        packed[pos] = ((d & 511) << 17) | sv;
    }
}

// ---- P4: per-bucket CSR finalize + xs1 = bf16(dinv*x).
__global__ __launch_bounds__(512) void csr_kernel(const int* __restrict__ packed,
                                                  const int* __restrict__ hist,
                                                  const int* __restrict__ bsum,
                                                  const float* __restrict__ x,
                                                  int* __restrict__ row_ptr,
                                                  float* __restrict__ dinv,
                                                  unsigned short* __restrict__ xs1,
                                                  int* __restrict__ col, int E) {
    __shared__ int cntL[512];
    __shared__ int rsL[512];
    __shared__ int fillL[512];
    __shared__ int boffL[SCAN_BLKS];
    __shared__ int srcL[CSR_CAP];   // 88 KB staging
    int t = threadIdx.x, b = blockIdx.x;
    int lo = b << BSHIFT;
    int nloc = min(512, N_NODES - lo);
    cntL[t] = 0;
    fillL[t] = 0;
    if (t < 64) {
        int orig = (t < SCAN_BLKS) ? bsum[t] : 0;
        int v = orig;
        for (int off = 1; off < 64; off <<= 1) {
            int up = __shfl_up(v, off);
            if (t >= off) v += up;
        }
        if (t < SCAN_BLKS) boffL[t] = v - orig;   // exclusive
    }
    __syncthreads();
    int i0 = b * NBLK;
    int start = hist[i0] + boffL[i0 >> 10];
    int end;
    if (b == NB_BUCKETS - 1) end = E;
    else {
        int i1 = (b + 1) * NBLK;
        end = hist[i1] + boffL[i1 >> 10];
    }
    for (int e = start + t; e < end; e += 512)
        atomicAdd(&cntL[packed[e] >> 17], 1);
    __syncthreads();
    int v = cntL[t];
    __syncthreads();
    for (int off = 1; off < 512; off <<= 1) {     // inclusive scan (Hillis-Steele)
        int add = (t >= off) ? cntL[t - off] : 0;
        __syncthreads();
        cntL[t] += add;
        __syncthreads();
    }
    int rowstart = start + cntL[t] - v;           // exclusive + bucket base
    rsL[t] = rowstart;
    if (t < nloc) {
        int node = lo + t;
        row_ptr[node] = rowstart;
        float d = rsqrtf((float)(v + 1));
        dinv[node] = d;
        const float4* xv = reinterpret_cast<const float4*>(x) + node * 2;
        float4 xa = xv[0], xb = xv[1];
        uint4 p;
        p.x = (unsigned)f2bf(xa.x * d) | ((unsigned)f2bf(xa.y * d) << 16);
        p.y = (unsigned)f2bf(xa.z * d) | ((unsigned)f2bf(xa.w * d) << 16);
        p.z = (unsigned)f2bf(xb.x * d) | ((unsigned)f2bf(xb.y * d) << 16);
        p.w = (unsigned)f2bf(xb.z * d) | ((unsigned)f2bf(xb.w * d) << 16);
        *reinterpret_cast<uint4*>(&xs1[node * 8]) = p;
    }
    if (b == NB_BUCKETS - 1 && t == 0) row_ptr[N_NODES] = E;
    __syncthreads();
    for (int e = start + t; e < end; e += 512) {
        int p = packed[e];
        int dl = p >> 17;
        int pos = rsL[dl] + atomicAdd(&fillL[dl], 1);
        int rel = pos - start;
        if (rel < CSR_CAP) srcL[rel] = p & 0x1FFFF;
        else col[pos] = p & 0x1FFFF;          // overflow fallback
    }
    __syncthreads();
    int lim = min(end - start, CSR_CAP);
    for (int i = t; i < lim; i += 512)
        col[start + i] = srcL[i];             // coalesced write-out
}

// Layer-1 aggregation FUSED with gemm1 (feature-per-lane, bf16 xs1).
__global__ __launch_bounds__(256) void agg8g1_kernel(
        const unsigned short* __restrict__ xs, const int* __restrict__ row_ptr,
        const int* __restrict__ col, const float* __restrict__ dinv,
        const float* __restrict__ W1, const float* __restrict__ b1,
        unsigned short* __restrict__ xs2, int n) {
    int wave = threadIdx.x >> 6;            // 4 waves/block = 4 nodes/block
    int node = blockIdx.x * 4 + wave;
    if (node >= n) return;
    int lane = threadIdx.x & 63;
    int f = lane & 7;          // feature index
    int s = lane >> 3;         // edge slot (octet)
    float w[8];
    float bias = b1[lane];
#pragma unroll
    for (int k = 0; k < 8; ++k) w[k] = W1[k * 64 + lane];   // L2-broadcast
    int e0 = row_ptr[node], e1 = row_ptr[node + 1];
    float a = (s == 0) ? bf2f(xs[node * 8 + f]) : 0.0f;     // self-loop, once
    int base = e0;
    for (; e1 - base > 48; base += 48) {    // rare fallback (P ~ 0.3%)
#pragma unroll
        for (int g = 0; g < 6; ++g) {
            int c = __builtin_nontemporal_load(&col[base + 8 * g + s]);
            a += bf2f(xs[c * 8 + f]);
        }
    }
    int rem = e1 - base;       // 0..48, wave-uniform
    if (rem > 0) {
        int e1m1 = e1 - 1;
        bool g4 = rem > 32, g5 = rem > 40;  // wave-uniform guards
        int i0 = base + s,      i1 = base + 8 + s,  i2 = base + 16 + s;
        int i3 = base + 24 + s, i4 = base + 32 + s, i5 = base + 40 + s;
        int c0 = __builtin_nontemporal_load(&col[min(i0, e1m1)]);
        int c1 = __builtin_nontemporal_load(&col[min(i1, e1m1)]);
        int c2 = __builtin_nontemporal_load(&col[min(i2, e1m1)]);
        int c3 = __builtin_nontemporal_load(&col[min(i3, e1m1)]);
        int c4 = 0, c5 = 0;
        if (g4) c4 = __builtin_nontemporal_load(&col[min(i4, e1m1)]);
        if (g5) c5 = __builtin_nontemporal_load(&col[min(i5, e1m1)]);
        float v0 = bf2f(xs[c0 * 8 + f]);
        float v1 = bf2f(xs[c1 * 8 + f]);
        float v2 = bf2f(xs[c2 * 8 + f]);
        float v3 = bf2f(xs[c3 * 8 + f]);
        float v4 = 0.f, v5 = 0.f;
        if (g4) v4 = bf2f(xs[c4 * 8 + f]);
        if (g5) v5 = bf2f(xs[c5 * 8 + f]);
        a += ((i0 < e1) ? v0 : 0.f) + ((i1 < e1) ? v1 : 0.f);
        a += ((i2 < e1) ? v2 : 0.f) + ((i3 < e1) ? v3 : 0.f);
        if (g4) a += (i4 < e1) ? v4 : 0.f;
        if (g5) a += (i5 < e1) ? v5 : 0.f;
    }
    // cross-slot reduce: lane ends holding z[f]
    a += __shfl_xor(a, 8);
    a += __shfl_xor(a, 16);
    a += __shfl_xor(a, 32);
    float d = dinv[node];
    float zd = a * d;
    float acc = bias;
#pragma unroll
    for (int k = 0; k < 8; ++k) acc += __shfl(zd, k) * w[k];
    xs2[node * 64 + lane] = f2bf(d * fmaxf(acc, 0.0f));
}

// D=64 aggregation over a bf16 feature table (rows = 128 B).
// Single-shot whole-row issue. Output bf16. Node range [n0,n1)
// (split into thirds this round for top-5 visibility).
__global__ __launch_bounds__(256) void agg64bf_kernel(
        const unsigned short* __restrict__ xs, const int* __restrict__ row_ptr,
        const int* __restrict__ col, const float* __restrict__ dinv,
        unsigned short* __restrict__ z, int n0, int n1) {
    int wave = threadIdx.x >> 6;            // 4 waves/block = 4 nodes/block
    int node = n0 + blockIdx.x * 4 + wave;
    if (node >= n1) return;
    int lane = threadIdx.x & 63;
    int j = lane >> 3, l = lane & 7;
    int e0 = row_ptr[node], e1 = row_ptr[node + 1];
    float a[8] = {0.f, 0.f, 0.f, 0.f, 0.f, 0.f, 0.f, 0.f};
    // self-row load issued first: shares the col-load wait
    uint4 sv = *reinterpret_cast<const uint4*>(&xs[node * 64 + 8 * l]);
    int base = e0;
    // rare fallback: keep remaining <= 48 edges (Poisson(32): ~0.2% of rows)
    for (; e1 - base > 48; base += 32) {
        int s0 = __builtin_nontemporal_load(&col[base + j]);
        int s1 = __builtin_nontemporal_load(&col[base + 8 + j]);
        int s2 = __builtin_nontemporal_load(&col[base + 16 + j]);
        int s3 = __builtin_nontemporal_load(&col[base + 24 + j]);
        uint4 v0 = *reinterpret_cast<const uint4*>(&xs[s0 * 64 + 8 * l]);
        uint4 v1 = *reinterpret_cast<const uint4*>(&xs[s1 * 64 + 8 * l]);
        uint4 v2 = *reinterpret_cast<const uint4*>(&xs[s2 * 64 + 8 * l]);
        uint4 v3 = *reinterpret_cast<const uint4*>(&xs[s3 * 64 + 8 * l]);
        acc_bf8(v0, 1.f, a); acc_bf8(v1, 1.f, a);
        acc_bf8(v2, 1.f, a); acc_bf8(v3, 1.f, a);
    }
    int rem = e1 - base;   // wave-uniform, 0..48
    if (rem > 0) {
        int e1m1 = e1 - 1;
        bool g4 = rem > 32, g5 = rem > 40;   // wave-uniform guards
        int i0 = base + j,      i1 = base + 8 + j;
        int i2 = base + 16 + j, i3 = base + 24 + j;
        int i4 = base + 32 + j, i5 = base + 40 + j;
        int c0 = __builtin_nontemporal_load(&col[min(i0, e1m1)]);
        int c1 = __builtin_nontemporal_load(&col[min(i1, e1m1)]);
        int c2 = __builtin_nontemporal_load(&col[min(i2, e1m1)]);
        int c3 = __builtin_nontemporal_load(&col[min(i3, e1m1)]);
        int c4 = 0, c5 = 0;
        if (g4) c4 = __builtin_nontemporal_load(&col[min(i4, e1m1)]);
        if (g5) c5 = __builtin_nontemporal_load(&col[min(i5, e1m1)]);
        uint4 v0 = *reinterpret_cast<const uint4*>(&xs[c0 * 64 + 8 * l]);
        uint4 v1 = *reinterpret_cast<const uint4*>(&xs[c1 * 64 + 8 * l]);
        uint4 v2 = *reinterpret_cast<const uint4*>(&xs[c2 * 64 + 8 * l]);
        uint4 v3 = *reinterpret_cast<const uint4*>(&xs[c3 * 64 + 8 * l]);
        uint4 v4, v5;
        if (g4) v4 = *reinterpret_cast<const uint4*>(&xs[c4 * 64 + 8 * l]);
        if (g5) v5 = *reinterpret_cast<const uint4*>(&xs[c5 * 64 + 8 * l]);
        acc_bf8(v0, (i0 < e1) ? 1.f : 0.f, a);
        acc_bf8(v1, (i1 < e1) ? 1.f : 0.f, a);
        acc_bf8(v2, (i2 < e1) ? 1.f : 0.f, a);
        acc_bf8(v3, (i3 < e1) ? 1.f : 0.f, a);
        if (g4) acc_bf8(v4, (i4 < e1) ? 1.f : 0.f, a);
        if (g5) acc_bf8(v5, (i5 < e1) ? 1.f : 0.f, a);
    }
    acc_bf8(sv, (j == 0) ? 1.f : 0.f, a);   // self-loop term, counted once
#pragma unroll
    for (int k = 0; k < 8; ++k) {
        a[k] += __shfl_xor(a[k], 8);
        a[k] += __shfl_xor(a[k], 16);
        a[k] += __shfl_xor(a[k], 32);
    }
    if (j == 0) {
        float d = dinv[node];
        uint4 p;
        p.x = (unsigned)f2bf(a[0] * d) | ((unsigned)f2bf(a[1] * d) << 16);
        p.y = (unsigned)f2bf(a[2] * d) | ((unsigned)f2bf(a[3] * d) << 16);
        p.z = (unsigned)f2bf(a[4] * d) | ((unsigned)f2bf(a[5] * d) << 16);
        p.w = (unsigned)f2bf(a[6] * d) | ((unsigned)f2bf(a[7] * d) << 16);
        *reinterpret_cast<uint4*>(&z[node * 64 + 8 * l]) = p;
    }
}

// FUSED layers 2+3 gemms: ys = dinv * ( relu(z2@W2+b2) @ W3 ).
// 64 rows/block, 4 waves x 16 rows. h2 tile (64x128 bf16) routed through
// LDS between the two MFMA stages. Weights pre-packed (bf16, padded) in
// global -> staged via plain uint4 copies (was 16K scalar cvt ops/block).
__global__ __launch_bounds__(256) void mgemm23_kernel(
        const unsigned short* __restrict__ X,   // z2 bf16 [N][64]
        const unsigned short* __restrict__ wpre,
        const float* __restrict__ b2, const float* __restrict__ dinv,
        unsigned short* __restrict__ Y,         // ys bf16 [N][64]
        int nrows) {
    __shared__ __align__(16) unsigned short WtL[WPRE_TOT];  // W2^T + W3^T (35.8 KB)
    __shared__ unsigned short h2L[64 * 136];                // h2 tile (17.4 KB)
    int tid = threadIdx.x;
    {   // stage prepacked weights: 2240 uint4s
        const uint4* src4 = reinterpret_cast<const uint4*>(wpre);
        uint4* dst4 = reinterpret_cast<uint4*>(WtL);
        for (int i = tid; i < WPRE_TOT / 8; i += 256) dst4[i] = src4[i];
    }
    __syncthreads();
    int wave = tid >> 6, lane = tid & 63;
    int row0 = blockIdx.x * 64 + wave * 16;
    int hl = lane >> 4, ll = lane & 15;
    // ---- stage 1: h2 = relu(z2 @ W2 + b2), K=64, M=128
    int arow = min(row0 + ll, nrows - 1);
    bf16x8 af0 = *reinterpret_cast<const bf16x8*>(&X[arow * 64 + hl * 8]);
    bf16x8 af1 = *reinterpret_cast<const bf16x8*>(&X[arow * 64 + 32 + hl * 8]);
    f32x4 acc1[8];
#pragma unroll
    for (int nt = 0; nt < 8; ++nt) {
        float bv = b2[nt * 16 + ll];
        acc1[nt] = {bv, bv, bv, bv};
    }
#pragma unroll
    for (int nt = 0; nt < 8; ++nt) {
        bf16x8 b0 = *reinterpret_cast<const bf16x8*>(&WtL[(nt * 16 + ll) * 72 + hl * 8]);
        bf16x8 b1 = *reinterpret_cast<const bf16x8*>(&WtL[(nt * 16 + ll) * 72 + 32 + hl * 8]);
        acc1[nt] = __builtin_amdgcn_mfma_f32_16x16x32_bf16(af0, b0, acc1[nt], 0, 0, 0);
        acc1[nt] = __builtin_amdgcn_mfma_f32_16x16x32_bf16(af1, b1, acc1[nt], 0, 0, 0);
    }
    // write h2 tile to LDS (C layout: col=nt*16+ll, row=wave*16+hl*4+r)
#pragma unroll
    for (int nt = 0; nt < 8; ++nt) {
#pragma unroll
        for (int r = 0; r < 4; ++r) {
            float v = fmaxf(acc1[nt][r], 0.0f);
            h2L[(wave * 16 + hl * 4 + r) * 136 + nt * 16 + ll] = f2bf(v);
        }
    }
    __syncthreads();
    // ---- stage 2: ys = dinv * (h2 @ W3), K=128, M=64
    bf16x8 af2[4];
#pragma unroll
    for (int ks = 0; ks < 4; ++ks)
        af2[ks] = *reinterpret_cast<const bf16x8*>(
            &h2L[(wave * 16 + ll) * 136 + ks * 32 + hl * 8]);
    f32x4 acc2[4];
#pragma unroll
    for (int nt = 0; nt < 4; ++nt) acc2[nt] = {0.f, 0.f, 0.f, 0.f};
#pragma unroll
    for (int nt = 0; nt < 4; ++nt) {
#pragma unroll
        for (int ks = 0; ks < 4; ++ks) {
            bf16x8 bf = *reinterpret_cast<const bf16x8*>(
                &WtL[WPRE_W3OFF + (nt * 16 + ll) * 136 + ks * 32 + hl * 8]);
            acc2[nt] = __builtin_amdgcn_mfma_f32_16x16x32_bf16(af2[ks], bf, acc2[nt], 0, 0, 0);
        }
    }
#pragma unroll
    for (int r = 0; r < 4; ++r) {
        int row = row0 + hl * 4 + r;
        if (row < nrows) {
            float d = dinv[row];
#pragma unroll
            for (int nt = 0; nt < 4; ++nt)
                Y[row * 64 + nt * 16 + ll] = f2bf(acc2[nt][r] * d);
        }
    }
}

// h3 = relu(z3 + b3); pool sums/counts per graph (bf16 z3, register
// pre-accumulation -- Guideline 12 proven form).
#define POOL_NPB 128   // nodes per block (32 per wave, contiguous)
__global__ __launch_bounds__(256) void pool_kernel(
        const unsigned short* __restrict__ z3, const float* __restrict__ b3,
        const int* __restrict__ batch, float* __restrict__ sums,
        float* __restrict__ cntf, int n) {
    int wave = threadIdx.x >> 6;
    int lane = threadIdx.x & 63;   // feature index
    int node0 = blockIdx.x * POOL_NPB + wave * 32;
    int nodeEnd = min(node0 + 32, n);
    if (node0 >= n) return;
    float bias = b3[lane];
    float acc = 0.0f, cnt = 0.0f;
    int curg = -1;
    for (int node = node0; node < nodeEnd; ++node) {
        int g = batch[node];               // wave-uniform (lane = feature)
        if (g != curg) {                   // wave-uniform branch
            if (curg >= 0) {
                atomicAdd(&sums[curg * 64 + lane], acc);
                if (lane == 0) atomicAdd(&cntf[curg], cnt);
            }
            curg = g; acc = 0.0f; cnt = 0.0f;
        }
        acc += fmaxf(bf2f(z3[node * 64 + lane]) + bias, 0.0f);
        cnt += 1.0f;
    }
    if (curg >= 0) {
        atomicAdd(&sums[curg * 64 + lane], acc);
        if (lane == 0) atomicAdd(&cntf[curg], cnt);
    }
}

// per-graph: g = sums/max(cnt,1); hid = relu(g@Wl1+bl1); out = hid@Wl2+bl2
__global__ void mlp_kernel(const float* __restrict__ sums, const float* __restrict__ cntf,
                           const float* __restrict__ Wl1, const float* __restrict__ bl1,
                           const float* __restrict__ Wl2, const float* __restrict__ bl2,
                           float* __restrict__ out) {
    __shared__ float gv[64];
    __shared__ float hid[32];
    int g = blockIdx.x, t = threadIdx.x;
    float denom = fmaxf(cntf[g], 1.0f);
    gv[t] = sums[g * 64 + t] / denom;
    __syncthreads();
    if (t < 32) {
        float a = bl1[t];
#pragma unroll
        for (int k = 0; k < 64; ++k) a += gv[k] * Wl1[k * 32 + t];
        hid[t] = fmaxf(a, 0.0f);
    }
    __syncthreads();
    if (t == 0) {
        float o = bl2[0];
#pragma unroll
        for (int k = 0; k < 32; ++k) o += hid[k] * Wl2[k];
        out[g] = o;
    }
}

extern "C" void kernel_launch(void* const* d_in, const int* in_sizes, int n_in,
                              void* d_out, int out_size, void* d_ws, size_t ws_size,
                              hipStream_t stream) {
    const float* x   = (const float*)d_in[0];
    const int* ei    = (const int*)d_in[1];
    const int* batch = (const int*)d_in[2];
    const float* W1  = (const float*)d_in[3];
    const float* b1  = (const float*)d_in[4];
    const float* W2  = (const float*)d_in[5];
    const float* b2  = (const float*)d_in[6];
    const float* W3  = (const float*)d_in[7];
    const float* b3  = (const float*)d_in[8];
    const float* Wl1 = (const float*)d_in[9];
    const float* bl1 = (const float*)d_in[10];
    const float* Wl2 = (const float*)d_in[11];
    const float* bl2 = (const float*)d_in[12];
    float* out = (float*)d_out;

    const int N = N_NODES;
    const int E = in_sizes[1] / 2;   // 3.2M
    const int* src = ei;
    const int* dst = ei + E;

    char* ws = (char*)d_ws;
    float* sums    = (float*)(ws + OFF_SUMS);
    float* cntf    = (float*)(ws + OFF_CNTF);
    int*   hist    = (int*)(ws + OFF_HIST);
    int*   bsum    = (int*)(ws + OFF_BSUM);
    int*   row_ptr = (int*)(ws + OFF_ROWPTR);
    float* dinv    = (float*)(ws + OFF_DINV);
    int*   col     = (int*)(ws + OFF_COL);
    unsigned short* xs1  = (unsigned short*)(ws + OFF_XS1);  // bf16
    unsigned short* wpre = (unsigned short*)(ws + OFF_WPRE); // prepacked W2^T/W3^T
    unsigned short* bufQ = (unsigned short*)(ws + OFF_BUFQ); // xs2, later ys
    unsigned short* bufR = (unsigned short*)(ws + OFF_BUFR); // z2, later z3
    int*   packed  = (int*)(ws + OFF_PAIRS);                 // aliases bufP

    // CSR build: hist(+zero) -> scanA(+wpre) -> bin -> csr(+xs1 scale)
    int epb = (E + NBLK - 1) / NBLK;   // 12500
    hist_kernel<<<NBLK, 256, 0, stream>>>(dst, hist, (int*)ws, E, epb);
    scanhA_kernel<<<SCAN_BLKS, 1024, 0, stream>>>(hist, bsum, W2, W3, wpre);
    bin_kernel<<<NBLK, 256, 0, stream>>>(src, dst, hist, bsum, packed, E, epb);
    csr_kernel<<<NB_BUCKETS, 512, 0, stream>>>(packed, hist, bsum, x,
                                               row_ptr, dinv, xs1, col, E);

    // Layer 1 (agg + gemm1 fused): xs2(bf16) = dinv*relu((agg xs1)@W1+b1)
    agg8g1_kernel<<<(N + 3) / 4, 256, 0, stream>>>(xs1, row_ptr, col, dinv, W1, b1,
                                                   bufQ, N);

    // Layer 2 agg: z2(bf16) = agg_bf16(xs2)  [3 diag splits]
    const int T = 33334;
    for (int q = 0; q < 3; ++q) {
        int n0 = q * T, n1 = min(n0 + T, N);
        agg64bf_kernel<<<(n1 - n0 + 3) / 4, 256, 0, stream>>>(
            bufQ, row_ptr, col, dinv, bufR, n0, n1);
    }

    // Layers 2+3 gemms FUSED: ys(bf16) = dinv*( relu(z2@W2+b2) @ W3 )
    mgemm23_kernel<<<1563, 256, 0, stream>>>(bufR, wpre, b2, dinv, bufQ, N);

    // Layer 3 agg: z3(bf16) = agg_bf16(ys)  [3 diag splits]
    for (int q = 0; q < 3; ++q) {
        int n0 = q * T, n1 = min(n0 + T, N);
        agg64bf_kernel<<<(n1 - n0 + 3) / 4, 256, 0, stream>>>(
            bufQ, row_ptr, col, dinv, bufR, n0, n1);
    }

    // Pool + MLP head
    pool_kernel<<<(N + POOL_NPB - 1) / POOL_NPB, 256, 0, stream>>>(
        bufR, b3, batch, sums, cntf, N);
    mlp_kernel<<<N_GRAPHS, 64, 0, stream>>>(sums, cntf, Wl1, bl1, Wl2, bl2, out);
}

// Round 16
// 351.003 us; speedup vs baseline: 1.0445x; 1.0445x over previous
//
#include <hip/hip_runtime.h>
#include <hip/hip_bf16.h>

#define N_NODES 100000
#define N_EDGES 3200000
#define N_GRAPHS 256
#define NB_BUCKETS 196      // ceil(100000 / 512)
#define BSHIFT 9            // 512 nodes per bucket
#define NBLK 256            // blocks for hist/bin passes
#define SCAN_BLKS 49        // 50176 / 1024
#define CSR_CAP 22528       // LDS staging capacity (88 KB); avg bucket 16.4K edges

// ---------------- workspace layout (bytes) ----------------
#define OFF_SUMS      0u            // float[256*64] pool sums (zeroed in hist)
#define OFF_CNTF      65536u        // float[256] pool counts (zeroed in hist)
#define ZERO_BYTES    66560u
#define OFF_HIST      66560u        // int[196*256] (bucket-major) per-(bucket,block) counts
#define OFF_BSUM      267264u       // int[64] scan block sums
#define OFF_ROWPTR    267776u       // int[N+1]
#define OFF_DINV      668160u       // float[N]
#define OFF_COL       1068544u     // int[E]
#define OFF_XS1       13868544u     // bf16[N*8]
#define OFF_WPRE      15468544u     // bf16 prepacked W2^T[128][72] + W3^T[64][136]
#define OFF_BUFQ      20268544u     // bf16 xs2 [N*64], later bf16 ys [N*64]
#define OFF_BUFR      45868544u     // bf16 z2 [N*64], later bf16 z3 [N*64]
#define OFF_BUFP      71468544u     // ALIASED: packed[E] only (h2 lives in LDS)
#define OFF_PAIRS     OFF_BUFP
// total ~97 MB

#define WPRE_W3OFF 9216             // ushort offset of W3^T inside wpre (128*72)
#define WPRE_TOT   17920            // total ushorts (9216 + 64*136)

typedef __attribute__((ext_vector_type(8))) short bf16x8;   // MFMA A/B frag (4 VGPRs)
typedef __attribute__((ext_vector_type(4))) float f32x4;    // MFMA C/D frag

// round-to-nearest-even float -> bf16 (values are finite; no NaN guard needed)
__device__ __forceinline__ unsigned short f2bf(float f) {
    unsigned u = __float_as_uint(f);
    return (unsigned short)((u + 0x7fffu + ((u >> 16) & 1u)) >> 16);
}

__device__ __forceinline__ float bf2f(unsigned short h) {
    return __uint_as_float(((unsigned)h) << 16);
}

// unpack uint4 (8 bf16) and accumulate m * value into a[0..7] (fp32)
__device__ __forceinline__ void acc_bf8(uint4 v, float m, float* a) {
    a[0] += m * __uint_as_float(v.x << 16);
    a[1] += m * __uint_as_float(v.x & 0xffff0000u);
    a[2] += m * __uint_as_float(v.y << 16);
    a[3] += m * __uint_as_float(v.y & 0xffff0000u);
    a[4] += m * __uint_as_float(v.z << 16);
    a[5] += m * __uint_as_float(v.z & 0xffff0000u);
    a[6] += m * __uint_as_float(v.w << 16);
    a[7] += m * __uint_as_float(v.w & 0xffff0000u);
}

// ---- P1: per-(bucket,block) histogram of dst. Also zeroes the pool
// accumulators.
__global__ __launch_bounds__(256) void hist_kernel(const int* __restrict__ dst,
                                                   int* __restrict__ hist,
                                                   int* __restrict__ zbase,
                                                   int E, int epb) {
    __shared__ int h[NB_BUCKETS];
    int t = threadIdx.x, blk = blockIdx.x;
    int gid = blk * 256 + t;
    if (gid < (int)(ZERO_BYTES / 4)) zbase[gid] = 0;
    if (t < NB_BUCKETS) h[t] = 0;
    __syncthreads();
    int e0 = blk * epb, e1 = min(e0 + epb, E);
    for (int e = e0 + t; e < e1; e += 256)
        atomicAdd(&h[__builtin_nontemporal_load(&dst[e]) >> BSHIFT], 1);
    __syncthreads();
    if (t < NB_BUCKETS) hist[t * NBLK + blk] = h[t];
}

// ---- P2: block-local exclusive scan of hist[50176] + per-block sums.
// Idle threads also pre-pack W2^T/W3^T to bf16 (one-time; feeds mgemm23).
__global__ __launch_bounds__(1024) void scanhA_kernel(int* __restrict__ hist,
                                                      int* __restrict__ bsum,
                                                      const float* __restrict__ W2,
                                                      const float* __restrict__ W3,
                                                      unsigned short* __restrict__ wpre) {
    __shared__ int s[1024];
    int t = threadIdx.x;
    int i = blockIdx.x * 1024 + t;     // 49*1024 == 50176 exactly
    // weight prepack (first 16384 global threads, overlaps the scan)
    if (i < 8192) {                    // W2^T [128][72]: Wt2[m][k] = W2[k][m]
        int m = i >> 6, k = i & 63;
        wpre[m * 72 + k] = f2bf(W2[k * 128 + m]);
    } else if (i < 16384) {            // W3^T [64][136]: Wt3[m][k] = W3[k][m]
        int ii = i - 8192;
        int m = ii >> 7, k = ii & 127;
        wpre[WPRE_W3OFF + m * 136 + k] = f2bf(W3[k * 64 + m]);
    }
    int v = hist[i];
    s[t] = v;
    __syncthreads();
    for (int off = 1; off < 1024; off <<= 1) {
        int add = (t >= off) ? s[t - off] : 0;
        __syncthreads();
        s[t] += add;
        __syncthreads();
    }
    hist[i] = s[t] - v;                // block-local exclusive
    if (t == 1023) bsum[blockIdx.x] = s[t];
}

// ---- P3: bin edges, PACKED (dl<<17 | src), local offset scan.
__global__ __launch_bounds__(256) void bin_kernel(const int* __restrict__ src,
                                                  const int* __restrict__ dst,
                                                  const int* __restrict__ hist,
                                                  const int* __restrict__ bsum,
                                                  int* __restrict__ packed, int E, int epb) {
    __shared__ int cur[NB_BUCKETS];
    __shared__ int boffL[SCAN_BLKS];
    int t = threadIdx.x, blk = blockIdx.x;
    if (t < 64) {
        int orig = (t < SCAN_BLKS) ? bsum[t] : 0;
        int v = orig;
        for (int off = 1; off < 64; off <<= 1) {
            int up = __shfl_up(v, off);
            if (t >= off) v += up;
        }
        if (t < SCAN_BLKS) boffL[t] = v - orig;   // exclusive
    }
    __syncthreads();
    if (t < NB_BUCKETS) {
        int i = t * NBLK + blk;
        cur[t] = hist[i] + boffL[i >> 10];
    }
    __syncthreads();
    int e0 = blk * epb, e1 = min(e0 + epb, E);
    for (int e = e0 + t; e < e1; e += 256) {
        int d = __builtin_nontemporal_load(&dst[e]);
        int sv = __builtin_nontemporal_load(&src[e]);
        int pos = atomicAdd(&cur[d >> BSHIFT], 1);
        packed[pos] = ((d & 511) << 17) | sv;
    }
}

// ---- P4: per-bucket CSR finalize + xs1 = bf16(dinv*x).
__global__ __launch_bounds__(512) void csr_kernel(const int* __restrict__ packed,
                                                  const int* __restrict__ hist,
                                                  const int* __restrict__ bsum,
                                                  const float* __restrict__ x,
                                                  int* __restrict__ row_ptr,
                                                  float* __restrict__ dinv,
                                                  unsigned short* __restrict__ xs1,
                                                  int* __restrict__ col, int E) {
    __shared__ int cntL[512];
    __shared__ int rsL[512];
    __shared__ int fillL[512];
    __shared__ int boffL[SCAN_BLKS];
    __shared__ int srcL[CSR_CAP];   // 88 KB staging
    int t = threadIdx.x, b = blockIdx.x;
    int lo = b << BSHIFT;
    int nloc = min(512, N_NODES - lo);
    cntL[t] = 0;
    fillL[t] = 0;
    if (t < 64) {
        int orig = (t < SCAN_BLKS) ? bsum[t] : 0;
        int v = orig;
        for (int off = 1; off < 64; off <<= 1) {
            int up = __shfl_up(v, off);
            if (t >= off) v += up;
        }
        if (t < SCAN_BLKS) boffL[t] = v - orig;   // exclusive
    }
    __syncthreads();
    int i0 = b * NBLK;
    int start = hist[i0] + boffL[i0 >> 10];
    int end;
    if (b == NB_BUCKETS - 1) end = E;
    else {
        int i1 = (b + 1) * NBLK;
        end = hist[i1] + boffL[i1 >> 10];
    }
    for (int e = start + t; e < end; e += 512)
        atomicAdd(&cntL[packed[e] >> 17], 1);
    __syncthreads();
    int v = cntL[t];
    __syncthreads();
    for (int off = 1; off < 512; off <<= 1) {     // inclusive scan (Hillis-Steele)
        int add = (t >= off) ? cntL[t - off] : 0;
        __syncthreads();
        cntL[t] += add;
        __syncthreads();
    }
    int rowstart = start + cntL[t] - v;           // exclusive + bucket base
    rsL[t] = rowstart;
    if (t < nloc) {
        int node = lo + t;
        row_ptr[node] = rowstart;
        float d = rsqrtf((float)(v + 1));
        dinv[node] = d;
        const float4* xv = reinterpret_cast<const float4*>(x) + node * 2;
        float4 xa = xv[0], xb = xv[1];
        uint4 p;
        p.x = (unsigned)f2bf(xa.x * d) | ((unsigned)f2bf(xa.y * d) << 16);
        p.y = (unsigned)f2bf(xa.z * d) | ((unsigned)f2bf(xa.w * d) << 16);
        p.z = (unsigned)f2bf(xb.x * d) | ((unsigned)f2bf(xb.y * d) << 16);
        p.w = (unsigned)f2bf(xb.z * d) | ((unsigned)f2bf(xb.w * d) << 16);
        *reinterpret_cast<uint4*>(&xs1[node * 8]) = p;
    }
    if (b == NB_BUCKETS - 1 && t == 0) row_ptr[N_NODES] = E;
    __syncthreads();
    for (int e = start + t; e < end; e += 512) {
        int p = packed[e];
        int dl = p >> 17;
        int pos = rsL[dl] + atomicAdd(&fillL[dl], 1);
        int rel = pos - start;
        if (rel < CSR_CAP) srcL[rel] = p & 0x1FFFF;
        else col[pos] = p & 0x1FFFF;          // overflow fallback
    }
    __syncthreads();
    int lim = min(end - start, CSR_CAP);
    for (int i = t; i < lim; i += 512)
        col[start + i] = srcL[i];             // coalesced write-out
}

// Layer-1 aggregation FUSED with gemm1 (feature-per-lane, bf16 xs1).
__global__ __launch_bounds__(256) void agg8g1_kernel(
        const unsigned short* __restrict__ xs, const int* __restrict__ row_ptr,
        const int* __restrict__ col, const float* __restrict__ dinv,
        const float* __restrict__ W1, const float* __restrict__ b1,
        unsigned short* __restrict__ xs2, int n) {
    int wave = threadIdx.x >> 6;            // 4 waves/block = 4 nodes/block
    int node = blockIdx.x * 4 + wave;
    if (node >= n) return;
    int lane = threadIdx.x & 63;
    int f = lane & 7;          // feature index
    int s = lane >> 3;         // edge slot (octet)
    float w[8];
    float bias = b1[lane];
#pragma unroll
    for (int k = 0; k < 8; ++k) w[k] = W1[k * 64 + lane];   // L2-broadcast
    int e0 = row_ptr[node], e1 = row_ptr[node + 1];
    float a = (s == 0) ? bf2f(xs[node * 8 + f]) : 0.0f;     // self-loop, once
    int base = e0;
    for (; e1 - base > 48; base += 48) {    // rare fallback (P ~ 0.3%)
#pragma unroll
        for (int g = 0; g < 6; ++g) {
            int c = __builtin_nontemporal_load(&col[base + 8 * g + s]);
            a += bf2f(xs[c * 8 + f]);
        }
    }
    int rem = e1 - base;       // 0..48, wave-uniform
    if (rem > 0) {
        int e1m1 = e1 - 1;
        bool g4 = rem > 32, g5 = rem > 40;  // wave-uniform guards
        int i0 = base + s,      i1 = base + 8 + s,  i2 = base + 16 + s;
        int i3 = base + 24 + s, i4 = base + 32 + s, i5 = base + 40 + s;
        int c0 = __builtin_nontemporal_load(&col[min(i0, e1m1)]);
        int c1 = __builtin_nontemporal_load(&col[min(i1, e1m1)]);
        int c2 = __builtin_nontemporal_load(&col[min(i2, e1m1)]);
        int c3 = __builtin_nontemporal_load(&col[min(i3, e1m1)]);
        int c4 = 0, c5 = 0;
        if (g4) c4 = __builtin_nontemporal_load(&col[min(i4, e1m1)]);
        if (g5) c5 = __builtin_nontemporal_load(&col[min(i5, e1m1)]);
        float v0 = bf2f(xs[c0 * 8 + f]);
        float v1 = bf2f(xs[c1 * 8 + f]);
        float v2 = bf2f(xs[c2 * 8 + f]);
        float v3 = bf2f(xs[c3 * 8 + f]);
        float v4 = 0.f, v5 = 0.f;
        if (g4) v4 = bf2f(xs[c4 * 8 + f]);
        if (g5) v5 = bf2f(xs[c5 * 8 + f]);
        a += ((i0 < e1) ? v0 : 0.f) + ((i1 < e1) ? v1 : 0.f);
        a += ((i2 < e1) ? v2 : 0.f) + ((i3 < e1) ? v3 : 0.f);
        if (g4) a += (i4 < e1) ? v4 : 0.f;
        if (g5) a += (i5 < e1) ? v5 : 0.f;
    }
    // cross-slot reduce: lane ends holding z[f]
    a += __shfl_xor(a, 8);
    a += __shfl_xor(a, 16);
    a += __shfl_xor(a, 32);
    float d = dinv[node];
    float zd = a * d;
    float acc = bias;
#pragma unroll
    for (int k = 0; k < 8; ++k) acc += __shfl(zd, k) * w[k];
    xs2[node * 64 + lane] = f2bf(d * fmaxf(acc, 0.0f));
}

// D=64 aggregation over a bf16 feature table (rows = 128 B).
// Single-shot whole-row issue. Output bf16.
__global__ __launch_bounds__(256) void agg64bf_kernel(
        const unsigned short* __restrict__ xs, const int* __restrict__ row_ptr,
        const int* __restrict__ col, const float* __restrict__ dinv,
        unsigned short* __restrict__ z, int n) {
    int wave = threadIdx.x >> 6;            // 4 waves/block = 4 nodes/block
    int node = blockIdx.x * 4 + wave;
    if (node >= n) return;
    int lane = threadIdx.x & 63;
    int j = lane >> 3, l = lane & 7;
    int e0 = row_ptr[node], e1 = row_ptr[node + 1];
    float a[8] = {0.f, 0.f, 0.f, 0.f, 0.f, 0.f, 0.f, 0.f};
    // self-row load issued first: shares the col-load wait
    uint4 sv = *reinterpret_cast<const uint4*>(&xs[node * 64 + 8 * l]);
    int base = e0;
    // rare fallback: keep remaining <= 48 edges (Poisson(32): ~0.2% of rows)
    for (; e1 - base > 48; base += 32) {
        int s0 = __builtin_nontemporal_load(&col[base + j]);
        int s1 = __builtin_nontemporal_load(&col[base + 8 + j]);
        int s2 = __builtin_nontemporal_load(&col[base + 16 + j]);
        int s3 = __builtin_nontemporal_load(&col[base + 24 + j]);
        uint4 v0 = *reinterpret_cast<const uint4*>(&xs[s0 * 64 + 8 * l]);
        uint4 v1 = *reinterpret_cast<const uint4*>(&xs[s1 * 64 + 8 * l]);
        uint4 v2 = *reinterpret_cast<const uint4*>(&xs[s2 * 64 + 8 * l]);
        uint4 v3 = *reinterpret_cast<const uint4*>(&xs[s3 * 64 + 8 * l]);
        acc_bf8(v0, 1.f, a); acc_bf8(v1, 1.f, a);
        acc_bf8(v2, 1.f, a); acc_bf8(v3, 1.f, a);
    }
    int rem = e1 - base;   // wave-uniform, 0..48
    if (rem > 0) {
        int e1m1 = e1 - 1;
        bool g4 = rem > 32, g5 = rem > 40;   // wave-uniform guards
        int i0 = base + j,      i1 = base + 8 + j;
        int i2 = base + 16 + j, i3 = base + 24 + j;
        int i4 = base + 32 + j, i5 = base + 40 + j;
        int c0 = __builtin_nontemporal_load(&col[min(i0, e1m1)]);
        int c1 = __builtin_nontemporal_load(&col[min(i1, e1m1)]);
        int c2 = __builtin_nontemporal_load(&col[min(i2, e1m1)]);
        int c3 = __builtin_nontemporal_load(&col[min(i3, e1m1)]);
        int c4 = 0, c5 = 0;
        if (g4) c4 = __builtin_nontemporal_load(&col[min(i4, e1m1)]);
        if (g5) c5 = __builtin_nontemporal_load(&col[min(i5, e1m1)]);
        uint4 v0 = *reinterpret_cast<const uint4*>(&xs[c0 * 64 + 8 * l]);
        uint4 v1 = *reinterpret_cast<const uint4*>(&xs[c1 * 64 + 8 * l]);
        uint4 v2 = *reinterpret_cast<const uint4*>(&xs[c2 * 64 + 8 * l]);
        uint4 v3 = *reinterpret_cast<const uint4*>(&xs[c3 * 64 + 8 * l]);
        uint4 v4, v5;
        if (g4) v4 = *reinterpret_cast<const uint4*>(&xs[c4 * 64 + 8 * l]);
        if (g5) v5 = *reinterpret_cast<const uint4*>(&xs[c5 * 64 + 8 * l]);
        acc_bf8(v0, (i0 < e1) ? 1.f : 0.f, a);
        acc_bf8(v1, (i1 < e1) ? 1.f : 0.f, a);
        acc_bf8(v2, (i2 < e1) ? 1.f : 0.f, a);
        acc_bf8(v3, (i3 < e1) ? 1.f : 0.f, a);
        if (g4) acc_bf8(v4, (i4 < e1) ? 1.f : 0.f, a);
        if (g5) acc_bf8(v5, (i5 < e1) ? 1.f : 0.f, a);
    }
    acc_bf8(sv, (j == 0) ? 1.f : 0.f, a);   // self-loop term, counted once
#pragma unroll
    for (int k = 0; k < 8; ++k) {
        a[k] += __shfl_xor(a[k], 8);
        a[k] += __shfl_xor(a[k], 16);
        a[k] += __shfl_xor(a[k], 32);
    }
    if (j == 0) {
        float d = dinv[node];
        uint4 p;
        p.x = (unsigned)f2bf(a[0] * d) | ((unsigned)f2bf(a[1] * d) << 16);
        p.y = (unsigned)f2bf(a[2] * d) | ((unsigned)f2bf(a[3] * d) << 16);
        p.z = (unsigned)f2bf(a[4] * d) | ((unsigned)f2bf(a[5] * d) << 16);
        p.w = (unsigned)f2bf(a[6] * d) | ((unsigned)f2bf(a[7] * d) << 16);
        *reinterpret_cast<uint4*>(&z[node * 64 + 8 * l]) = p;
    }
}

// FUSED layers 2+3 gemms: ys = dinv * ( relu(z2@W2+b2) @ W3 ).
// 64 rows/block, 4 waves x 16 rows. h2 tile (64x128 bf16) routed through
// LDS between the two MFMA stages. Weights pre-packed (bf16, padded) in
// global -> staged via plain uint4 copies.
__global__ __launch_bounds__(256) void mgemm23_kernel(
        const unsigned short* __restrict__ X,   // z2 bf16 [N][64]
        const unsigned short* __restrict__ wpre,
        const float* __restrict__ b2, const float* __restrict__ dinv,
        unsigned short* __restrict__ Y,         // ys bf16 [N][64]
        int nrows) {
    __shared__ __align__(16) unsigned short WtL[WPRE_TOT];  // W2^T + W3^T (35.8 KB)
    __shared__ unsigned short h2L[64 * 136];                // h2 tile (17.4 KB)
    int tid = threadIdx.x;
    {   // stage prepacked weights: 2240 uint4s
        const uint4* src4 = reinterpret_cast<const uint4*>(wpre);
        uint4* dst4 = reinterpret_cast<uint4*>(WtL);
        for (int i = tid; i < WPRE_TOT / 8; i += 256) dst4[i] = src4[i];
    }
    __syncthreads();
    int wave = tid >> 6, lane = tid & 63;
    int row0 = blockIdx.x * 64 + wave * 16;
    int hl = lane >> 4, ll = lane & 15;
    // ---- stage 1: h2 = relu(z2 @ W2 + b2), K=64, M=128
    int arow = min(row0 + ll, nrows - 1);
    bf16x8 af0 = *reinterpret_cast<const bf16x8*>(&X[arow * 64 + hl * 8]);
    bf16x8 af1 = *reinterpret_cast<const bf16x8*>(&X[arow * 64 + 32 + hl * 8]);
    f32x4 acc1[8];
#pragma unroll
    for (int nt = 0; nt < 8; ++nt) {
        float bv = b2[nt * 16 + ll];
        acc1[nt] = {bv, bv, bv, bv};
    }
#pragma unroll
    for (int nt = 0; nt < 8; ++nt) {
        bf16x8 b0 = *reinterpret_cast<const bf16x8*>(&WtL[(nt * 16 + ll) * 72 + hl * 8]);
        bf16x8 b1 = *reinterpret_cast<const bf16x8*>(&WtL[(nt * 16 + ll) * 72 + 32 + hl * 8]);
        acc1[nt] = __builtin_amdgcn_mfma_f32_16x16x32_bf16(af0, b0, acc1[nt], 0, 0, 0);
        acc1[nt] = __builtin_amdgcn_mfma_f32_16x16x32_bf16(af1, b1, acc1[nt], 0, 0, 0);
    }
    // write h2 tile to LDS (C layout: col=nt*16+ll, row=wave*16+hl*4+r)
#pragma unroll
    for (int nt = 0; nt < 8; ++nt) {
#pragma unroll
        for (int r = 0; r < 4; ++r) {
            float v = fmaxf(acc1[nt][r], 0.0f);
            h2L[(wave * 16 + hl * 4 + r) * 136 + nt * 16 + ll] = f2bf(v);
        }
    }
    __syncthreads();
    // ---- stage 2: ys = dinv * (h2 @ W3), K=128, M=64
    bf16x8 af2[4];
#pragma unroll
    for (int ks = 0; ks < 4; ++ks)
        af2[ks] = *reinterpret_cast<const bf16x8*>(
            &h2L[(wave * 16 + ll) * 136 + ks * 32 + hl * 8]);
    f32x4 acc2[4];
#pragma unroll
    for (int nt = 0; nt < 4; ++nt) acc2[nt] = {0.f, 0.f, 0.f, 0.f};
#pragma unroll
    for (int nt = 0; nt < 4; ++nt) {
#pragma unroll
        for (int ks = 0; ks < 4; ++ks) {
            bf16x8 bf = *reinterpret_cast<const bf16x8*>(
                &WtL[WPRE_W3OFF + (nt * 16 + ll) * 136 + ks * 32 + hl * 8]);
            acc2[nt] = __builtin_amdgcn_mfma_f32_16x16x32_bf16(af2[ks], bf, acc2[nt], 0, 0, 0);
        }
    }
#pragma unroll
    for (int r = 0; r < 4; ++r) {
        int row = row0 + hl * 4 + r;
        if (row < nrows) {
            float d = dinv[row];
#pragma unroll
            for (int nt = 0; nt < 4; ++nt)
                Y[row * 64 + nt * 16 + ll] = f2bf(acc2[nt][r] * d);
        }
    }
}

// h3 = relu(z3 + b3); pool sums/counts per graph (bf16 z3, register
// pre-accumulation -- Guideline 12 proven form).
#define POOL_NPB 128   // nodes per block (32 per wave, contiguous)
__global__ __launch_bounds__(256) void pool_kernel(
        const unsigned short* __restrict__ z3, const float* __restrict__ b3,
        const int* __restrict__ batch, float* __restrict__ sums,
        float* __restrict__ cntf, int n) {
    int wave = threadIdx.x >> 6;
    int lane = threadIdx.x & 63;   // feature index
    int node0 = blockIdx.x * POOL_NPB + wave * 32;
    int nodeEnd = min(node0 + 32, n);
    if (node0 >= n) return;
    float bias = b3[lane];
    float acc = 0.0f, cnt = 0.0f;
    int curg = -1;
    for (int node = node0; node < nodeEnd; ++node) {
        int g = batch[node];               // wave-uniform (lane = feature)
        if (g != curg) {                   // wave-uniform branch
            if (curg >= 0) {
                atomicAdd(&sums[curg * 64 + lane], acc);
                if (lane == 0) atomicAdd(&cntf[curg], cnt);
            }
            curg = g; acc = 0.0f; cnt = 0.0f;
        }
        acc += fmaxf(bf2f(z3[node * 64 + lane]) + bias, 0.0f);
        cnt += 1.0f;
    }
    if (curg >= 0) {
        atomicAdd(&sums[curg * 64 + lane], acc);
        if (lane == 0) atomicAdd(&cntf[curg], cnt);
    }
}

// per-graph: g = sums/max(cnt,1); hid = relu(g@Wl1+bl1); out = hid@Wl2+bl2
__global__ void mlp_kernel(const float* __restrict__ sums, const float* __restrict__ cntf,
                           const float* __restrict__ Wl1, const float* __restrict__ bl1,
                           const float* __restrict__ Wl2, const float* __restrict__ bl2,
                           float* __restrict__ out) {
    __shared__ float gv[64];
    __shared__ float hid[32];
    int g = blockIdx.x, t = threadIdx.x;
    float denom = fmaxf(cntf[g], 1.0f);
    gv[t] = sums[g * 64 + t] / denom;
    __syncthreads();
    if (t < 32) {
        float a = bl1[t];
#pragma unroll
        for (int k = 0; k < 64; ++k) a += gv[k] * Wl1[k * 32 + t];
        hid[t] = fmaxf(a, 0.0f);
    }
    __syncthreads();
    if (t == 0) {
        float o = bl2[0];
#pragma unroll
        for (int k = 0; k < 32; ++k) o += hid[k] * Wl2[k];
        out[g] = o;
    }
}

extern "C" void kernel_launch(void* const* d_in, const int* in_sizes, int n_in,
                              void* d_out, int out_size, void* d_ws, size_t ws_size,
                              hipStream_t stream) {
    const float* x   = (const float*)d_in[0];
    const int* ei    = (const int*)d_in[1];
    const int* batch = (const int*)d_in[2];
    const float* W1  = (const float*)d_in[3];
    const float* b1  = (const float*)d_in[4];
    const float* W2  = (const float*)d_in[5];
    const float* b2  = (const float*)d_in[6];
    const float* W3  = (const float*)d_in[7];
    const float* b3  = (const float*)d_in[8];
    const float* Wl1 = (const float*)d_in[9];
    const float* bl1 = (const float*)d_in[10];
    const float* Wl2 = (const float*)d_in[11];
    const float* bl2 = (const float*)d_in[12];
    float* out = (float*)d_out;

    const int N = N_NODES;
    const int E = in_sizes[1] / 2;   // 3.2M
    const int* src = ei;
    const int* dst = ei + E;

    char* ws = (char*)d_ws;
    float* sums    = (float*)(ws + OFF_SUMS);
    float* cntf    = (float*)(ws + OFF_CNTF);
    int*   hist    = (int*)(ws + OFF_HIST);
    int*   bsum    = (int*)(ws + OFF_BSUM);
    int*   row_ptr = (int*)(ws + OFF_ROWPTR);
    float* dinv    = (float*)(ws + OFF_DINV);
    int*   col     = (int*)(ws + OFF_COL);
    unsigned short* xs1  = (unsigned short*)(ws + OFF_XS1);  // bf16
    unsigned short* wpre = (unsigned short*)(ws + OFF_WPRE); // prepacked W2^T/W3^T
    unsigned short* bufQ = (unsigned short*)(ws + OFF_BUFQ); // xs2, later ys
    unsigned short* bufR = (unsigned short*)(ws + OFF_BUFR); // z2, later z3
    int*   packed  = (int*)(ws + OFF_PAIRS);                 // aliases bufP

    // CSR build: hist(+zero) -> scanA(+wpre) -> bin -> csr(+xs1 scale)
    int epb = (E + NBLK - 1) / NBLK;   // 12500
    hist_kernel<<<NBLK, 256, 0, stream>>>(dst, hist, (int*)ws, E, epb);
    scanhA_kernel<<<SCAN_BLKS, 1024, 0, stream>>>(hist, bsum, W2, W3, wpre);
    bin_kernel<<<NBLK, 256, 0, stream>>>(src, dst, hist, bsum, packed, E, epb);
    csr_kernel<<<NB_BUCKETS, 512, 0, stream>>>(packed, hist, bsum, x,
                                               row_ptr, dinv, xs1, col, E);

    // Layer 1 (agg + gemm1 fused): xs2(bf16) = dinv*relu((agg xs1)@W1+b1)
    agg8g1_kernel<<<(N + 3) / 4, 256, 0, stream>>>(xs1, row_ptr, col, dinv, W1, b1,
                                                   bufQ, N);

    // Layer 2 agg: z2(bf16) = agg_bf16(xs2)
    agg64bf_kernel<<<(N + 3) / 4, 256, 0, stream>>>(
        bufQ, row_ptr, col, dinv, bufR, N);

    // Layers 2+3 gemms FUSED: ys(bf16) = dinv*( relu(z2@W2+b2) @ W3 )
    mgemm23_kernel<<<1563, 256, 0, stream>>>(bufR, wpre, b2, dinv, bufQ, N);

    // Layer 3 agg: z3(bf16) = agg_bf16(ys)   (z2 dead -> reuse bufR)
    agg64bf_kernel<<<(N + 3) / 4, 256, 0, stream>>>(
        bufQ, row_ptr, col, dinv, bufR, N);

    // Pool + MLP head
    pool_kernel<<<(N + POOL_NPB - 1) / POOL_NPB, 256, 0, stream>>>(
        bufR, b3, batch, sums, cntf, N);
    mlp_kernel<<<N_GRAPHS, 64, 0, stream>>>(sums, cntf, Wl1, bl1, Wl2, bl2, out);
}